// Round 8
// baseline (321.270 us; speedup 1.0000x reference)
//
#include <hip/hip_runtime.h>
#include <hip/hip_bf16.h>
#include <math.h>

#define T_ 16
#define B_ 16
#define N_ 256
#define H_ 512
#define L_ 64
#define K_ 8
#define SCALE 0.04419417382415922f   // THETA / sqrt(512)

// ---- DPP helper ----
template <int CTRL>
__device__ __forceinline__ float dpp_mov(float x) {
  return __int_as_float(
      __builtin_amdgcn_update_dpp(0, __float_as_int(x), CTRL, 0xF, 0xF, false));
}

// 16-lane (DPP-row) inclusive sum; lane 15 of each 16-lane row holds the total.
__device__ __forceinline__ float reduce16(float v) {
  v += dpp_mov<0x111>(v);  // row_shr:1
  v += dpp_mov<0x112>(v);  // row_shr:2
  v += dpp_mov<0x114>(v);  // row_shr:4
  v += dpp_mov<0x118>(v);  // row_shr:8
  return v;
}

// ============================================================================
// Fused kernel: score (R6 structure, unchanged) + last-block-per-b finisher.
//
// Score part: one WAVE per (b,n) tile; 4 waves/block share one b (32KB q LDS).
// r = lane>>4 row-group, c = lane&15 h-chunk; 4 rows per group per pass so one
// broadcast ds_read_b128 of q feeds 16 FMAs; continuous flattened prefetch;
// running max in per-wave LDS psum.
//
// Finisher: after storing raw scores, every thread fences (agent release,
// buffer_wbl2), block syncs, thread 0 takes a ticket on counter[b] (device-
// scope atomic). Ticket 63 (all 64 b-blocks done) acquires (buffer_inv) and
// runs softmax+topk for all 16 t-rows of b — replaces the 2nd launch (~7us).
// Finisher identity is nondeterministic; its input/output are not (G16 pattern).
//
// Register-pressure discipline (hard-won):
//   R2: (256,4) => 64-VGPR cap => acc spill (4.2GB scratch)
//   R3: no bound => full unroll, VGPR=256 + 2KB/thread scratch
//   Fix: unroll 1 on streaming loops + (256,2) => 128-VGPR ceiling.
// ============================================================================
__global__ __launch_bounds__(256, 2) void fused_kernel(
    const float* __restrict__ q, const float* __restrict__ keys,
    float* __restrict__ att, float* __restrict__ out_idx,
    unsigned int* __restrict__ counters) {
  __shared__ float qs[8192];           // [chunk][t][c] float4 = 32 KB
  __shared__ float psum[4][4][4][16];  // [wave][gp][group][t] = 4 KB
  __shared__ unsigned int ticket_s;

  const int bid  = blockIdx.x;   // 0..1023
  const int b    = bid >> 6;
  const int wave = threadIdx.x >> 6;
  const int lane = threadIdx.x & 63;
  const int n    = ((bid & 63) << 2) | wave;

  // ---- stage q[b]: qs[((ch*16 + t)*16 + c)] (float4 units) ----
  {
    const int tid = threadIdx.x;
#pragma unroll
    for (int k = 0; k < 8; ++k) {
      const int flat = tid + (k << 8);       // float4 index, 0..2047
      const int c  = flat & 15;
      const int t  = (flat >> 4) & 15;
      const int ch = flat >> 8;
      const float4 v =
          *(const float4*)(q + ((size_t)t * B_ + b) * H_ + ch * 64 + c * 4);
      *(float4*)(qs + (size_t)flat * 4) = v;
    }
  }
  __syncthreads();

  const int r = lane >> 4;
  const int c = lane & 15;
  const float* __restrict__ kb =
      keys + ((size_t)n * B_ + b) * (size_t)(L_ * H_);
  // group r's sub-row i (= 16gp + 4i + r) chunk ch lives at
  //   pbase + gp*8192 + i*2048 + ch*64      (float offsets)
  const float* __restrict__ pbase = kb + (size_t)r * H_ + c * 4;

  float4 k0 = *(const float4*)(pbase + 0);
  float4 k1 = *(const float4*)(pbase + 2048);
  float4 k2 = *(const float4*)(pbase + 4096);
  float4 k3 = *(const float4*)(pbase + 6144);

#pragma unroll 1
  for (int gp = 0; gp < 4; ++gp) {
    float acc0[T_], acc1[T_], acc2[T_], acc3[T_];
#pragma unroll
    for (int t = 0; t < T_; ++t) acc0[t] = acc1[t] = acc2[t] = acc3[t] = 0.0f;

#pragma unroll 1
    for (int ch = 0; ch < 8; ++ch) {
      // flattened successor of (gp,ch); wrap to 0 at the very end (in-bounds)
      const int nxt = (ch < 7) ? ((gp << 13) + ((ch + 1) << 6))
                               : ((gp < 3) ? ((gp + 1) << 13) : 0);
      const float4 n0 = *(const float4*)(pbase + nxt);
      const float4 n1 = *(const float4*)(pbase + nxt + 2048);
      const float4 n2 = *(const float4*)(pbase + nxt + 4096);
      const float4 n3 = *(const float4*)(pbase + nxt + 6144);

      const float* qv = qs + (ch << 10);  // qs[ch][0][0]
#pragma unroll
      for (int t = 0; t < T_; ++t) {
        const float4 q4 = *(const float4*)(qv + (((t << 4) + c) << 2));
        acc0[t] = fmaf(k0.x, q4.x,
                  fmaf(k0.y, q4.y, fmaf(k0.z, q4.z, fmaf(k0.w, q4.w, acc0[t]))));
        acc1[t] = fmaf(k1.x, q4.x,
                  fmaf(k1.y, q4.y, fmaf(k1.z, q4.z, fmaf(k1.w, q4.w, acc1[t]))));
        acc2[t] = fmaf(k2.x, q4.x,
                  fmaf(k2.y, q4.y, fmaf(k2.z, q4.z, fmaf(k2.w, q4.w, acc2[t]))));
        acc3[t] = fmaf(k3.x, q4.x,
                  fmaf(k3.y, q4.y, fmaf(k3.z, q4.z, fmaf(k3.w, q4.w, acc3[t]))));
      }
      k0 = n0;
      k1 = n1;
      k2 = n2;
      k3 = n3;
    }

    // 16-lane reduce (4 rows per group, 4 groups in parallel); c==15 has sums
#pragma unroll
    for (int t = 0; t < T_; ++t) {
      const float s0 = reduce16(acc0[t]);
      const float s1 = reduce16(acc1[t]);
      const float s2 = reduce16(acc2[t]);
      const float s3 = reduce16(acc3[t]);
      if (c == 15)
        psum[wave][gp][r][t] = fmaxf(fmaxf(s0, s1), fmaxf(s2, s3));
    }
  }

  // epilogue: gather this wave's 16 per-(gp,group) maxima per t
  if (lane < 16) {
    float m = -3.4e38f;
#pragma unroll
    for (int gp = 0; gp < 4; ++gp)
#pragma unroll
      for (int g = 0; g < 4; ++g) m = fmaxf(m, psum[wave][gp][g][lane]);
    att[(size_t)lane * (B_ * N_) + b * N_ + n] = m;  // raw score, (T,B,N)
  }

  // ---- last-block-per-b finisher protocol ----
  __threadfence();   // release: all threads flush their score stores (wbl2)
  __syncthreads();   // all stores + fences of the block done
  if (threadIdx.x == 0) ticket_s = atomicAdd(&counters[b], 1u);
  __syncthreads();
  if (ticket_s != 63u) return;

  __threadfence();   // acquire: invalidate stale L1/L2 lines (buffer_inv)

  // softmax + top-8 for the 16 t-rows of this b; wave handles rows wave+4k
#pragma unroll 1
  for (int tt = wave; tt < T_; tt += 4) {
    float* s = att + ((size_t)tt * B_ + b) * N_;
    const float4 v4 = *(const float4*)(s + 4 * lane);
    const float v[4] = {v4.x, v4.y, v4.z, v4.w};

    float m = fmaxf(fmaxf(v[0], v[1]), fmaxf(v[2], v[3]));
#pragma unroll
    for (int d = 1; d < 64; d <<= 1) m = fmaxf(m, __shfl_xor(m, d));

    float p[4];
#pragma unroll
    for (int e = 0; e < 4; ++e) p[e] = expf(SCALE * (v[e] - m));

    float sum = p[0] + p[1] + p[2] + p[3];
#pragma unroll
    for (int d = 1; d < 64; d <<= 1) sum += __shfl_xor(sum, d);
    const float inv = 1.0f / sum;

    float a[4];
#pragma unroll
    for (int e = 0; e < 4; ++e) a[e] = p[e] * inv;

    *(float4*)(s + 4 * lane) = make_float4(a[0], a[1], a[2], a[3]);

    // top-8: repeated wave argmax (value desc, index asc on ties)
    float w[4] = {a[0], a[1], a[2], a[3]};
#pragma unroll 1
    for (int kk = 0; kk < K_; ++kk) {
      float bv = w[0];
      int bn = 4 * lane;
#pragma unroll
      for (int e = 1; e < 4; ++e) {
        if (w[e] > bv) { bv = w[e]; bn = 4 * lane + e; }
      }
#pragma unroll
      for (int d = 1; d < 64; d <<= 1) {
        const float ov = __shfl_xor(bv, d);
        const int on = __shfl_xor(bn, d);
        if (ov > bv || (ov == bv && on < bn)) { bv = ov; bn = on; }
      }
      if (lane == 0)
        out_idx[kk * (T_ * B_) + tt * B_ + b] = (float)bn;  // (k,T,B)
#pragma unroll
      for (int e = 0; e < 4; ++e)
        if (4 * lane + e == bn) w[e] = -1.0f;
    }
  }
}

extern "C" void kernel_launch(void* const* d_in, const int* in_sizes, int n_in,
                              void* d_out, int out_size, void* d_ws,
                              size_t ws_size, hipStream_t stream) {
  const float* q    = (const float*)d_in[0];   // (T,1,B,H) fp32
  const float* keys = (const float*)d_in[1];   // (N,B,L*H) fp32
  float* out = (float*)d_out;
  float* att = out;                 // 65536 floats: raw scores -> attention
  float* idx = out + T_ * B_ * N_;  // 2048 floats: (k,T,B) indices as floats
  unsigned int* counters = (unsigned int*)d_ws;  // 16 uints, zeroed per call

  hipMemsetAsync(counters, 0, B_ * sizeof(unsigned int), stream);
  fused_kernel<<<B_ * (N_ / 4), 256, 0, stream>>>(q, keys, att, idx, counters);
}

// Round 9
// 100.172 us; speedup vs baseline: 3.2072x; 3.2072x over previous
//
#include <hip/hip_runtime.h>
#include <hip/hip_bf16.h>
#include <math.h>

#define T_ 16
#define B_ 16
#define N_ 256
#define H_ 512
#define L_ 64
#define K_ 8
#define SCALE 0.04419417382415922f   // THETA / sqrt(512)

// ---- DPP helper ----
template <int CTRL>
__device__ __forceinline__ float dpp_mov(float x) {
  return __int_as_float(
      __builtin_amdgcn_update_dpp(0, __float_as_int(x), CTRL, 0xF, 0xF, false));
}

// 16-lane (DPP-row) inclusive sum; lane 15 of each 16-lane row holds the total.
__device__ __forceinline__ float reduce16(float v) {
  v += dpp_mov<0x111>(v);  // row_shr:1
  v += dpp_mov<0x112>(v);  // row_shr:2
  v += dpp_mov<0x114>(v);  // row_shr:4
  v += dpp_mov<0x118>(v);  // row_shr:8
  return v;
}

// Nontemporal float4 load (keys are stream-once: bypass L1/L2 allocation).
typedef float f4v __attribute__((ext_vector_type(4)));
__device__ __forceinline__ f4v ntload(const float* p) {
  return __builtin_nontemporal_load((const f4v*)p);
}

// ============================================================================
// Kernel 1 (= R6 structure, reverted from the failed R7/R8 fusion):
// one WAVE per (b,n) tile; 4 waves/block share one b (32KB q LDS).
// r = lane>>4 row-group, c = lane&15 h-chunk; 4 rows per group per pass so one
// broadcast ds_read_b128 of q feeds 16 FMAs; continuous flattened prefetch;
// running max in per-wave LDS psum.  Keys loaded nontemporal (zero reuse).
//
// Register-pressure discipline (hard-won):
//   R2: (256,4) => 64-VGPR cap => acc spill (4.2GB scratch)
//   R3: no bound => full unroll, VGPR=256 + 2KB/thread scratch
//   R8: fused finisher => allocator VOLUNTARILY chose 64-VGPR class => spill
//   Fix: unroll 1 on streaming loops + (256,2) + keep the kernel lean so the
//   allocator stays in the 128-VGPR class (live state ~118 floats).
// ============================================================================
__global__ __launch_bounds__(256, 2) void score_kernel(
    const float* __restrict__ q, const float* __restrict__ keys,
    float* __restrict__ scores) {
  __shared__ float qs[8192];           // [chunk][t][c] float4 = 32 KB
  __shared__ float psum[4][4][4][16];  // [wave][gp][group][t] = 4 KB

  const int bid  = blockIdx.x;   // 0..1023
  const int b    = bid >> 6;
  const int wave = threadIdx.x >> 6;
  const int lane = threadIdx.x & 63;
  const int n    = ((bid & 63) << 2) | wave;

  // ---- stage q[b]: qs[((ch*16 + t)*16 + c)] (float4 units) ----
  {
    const int tid = threadIdx.x;
#pragma unroll
    for (int k = 0; k < 8; ++k) {
      const int flat = tid + (k << 8);       // float4 index, 0..2047
      const int c  = flat & 15;
      const int t  = (flat >> 4) & 15;
      const int ch = flat >> 8;
      const float4 v =
          *(const float4*)(q + ((size_t)t * B_ + b) * H_ + ch * 64 + c * 4);
      *(float4*)(qs + (size_t)flat * 4) = v;
    }
  }
  __syncthreads();

  const int r = lane >> 4;
  const int c = lane & 15;
  const float* __restrict__ kb =
      keys + ((size_t)n * B_ + b) * (size_t)(L_ * H_);
  // group r's sub-row i (= 16gp + 4i + r) chunk ch lives at
  //   pbase + gp*8192 + i*2048 + ch*64      (float offsets)
  const float* __restrict__ pbase = kb + (size_t)r * H_ + c * 4;

  f4v k0 = ntload(pbase + 0);
  f4v k1 = ntload(pbase + 2048);
  f4v k2 = ntload(pbase + 4096);
  f4v k3 = ntload(pbase + 6144);

#pragma unroll 1
  for (int gp = 0; gp < 4; ++gp) {
    float acc0[T_], acc1[T_], acc2[T_], acc3[T_];
#pragma unroll
    for (int t = 0; t < T_; ++t) acc0[t] = acc1[t] = acc2[t] = acc3[t] = 0.0f;

#pragma unroll 1
    for (int ch = 0; ch < 8; ++ch) {
      // flattened successor of (gp,ch); wrap to 0 at the very end (in-bounds)
      const int nxt = (ch < 7) ? ((gp << 13) + ((ch + 1) << 6))
                               : ((gp < 3) ? ((gp + 1) << 13) : 0);
      const f4v n0 = ntload(pbase + nxt);
      const f4v n1 = ntload(pbase + nxt + 2048);
      const f4v n2 = ntload(pbase + nxt + 4096);
      const f4v n3 = ntload(pbase + nxt + 6144);

      const float* qv = qs + (ch << 10);  // qs[ch][0][0]
#pragma unroll
      for (int t = 0; t < T_; ++t) {
        const float4 q4 = *(const float4*)(qv + (((t << 4) + c) << 2));
        acc0[t] = fmaf(k0.x, q4.x,
                  fmaf(k0.y, q4.y, fmaf(k0.z, q4.z, fmaf(k0.w, q4.w, acc0[t]))));
        acc1[t] = fmaf(k1.x, q4.x,
                  fmaf(k1.y, q4.y, fmaf(k1.z, q4.z, fmaf(k1.w, q4.w, acc1[t]))));
        acc2[t] = fmaf(k2.x, q4.x,
                  fmaf(k2.y, q4.y, fmaf(k2.z, q4.z, fmaf(k2.w, q4.w, acc2[t]))));
        acc3[t] = fmaf(k3.x, q4.x,
                  fmaf(k3.y, q4.y, fmaf(k3.z, q4.z, fmaf(k3.w, q4.w, acc3[t]))));
      }
      k0 = n0;
      k1 = n1;
      k2 = n2;
      k3 = n3;
    }

    // 16-lane reduce (4 rows per group, 4 groups in parallel); c==15 has sums
#pragma unroll
    for (int t = 0; t < T_; ++t) {
      const float s0 = reduce16(acc0[t]);
      const float s1 = reduce16(acc1[t]);
      const float s2 = reduce16(acc2[t]);
      const float s3 = reduce16(acc3[t]);
      if (c == 15)
        psum[wave][gp][r][t] = fmaxf(fmaxf(s0, s1), fmaxf(s2, s3));
    }
  }

  // epilogue: gather this wave's 16 per-(gp,group) maxima per t (same-wave
  // LDS dependence -> compiler-inserted lgkmcnt; no barrier needed)
  if (lane < 16) {
    float m = -3.4e38f;
#pragma unroll
    for (int gp = 0; gp < 4; ++gp)
#pragma unroll
      for (int g = 0; g < 4; ++g) m = fmaxf(m, psum[wave][gp][g][lane]);
    scores[(size_t)lane * (B_ * N_) + b * N_ + n] = m;  // raw score, (T,B,N)
  }
}

// ============================================================================
// Kernel 2: one wave per (t,b) row.  In-place softmax over N=256, then top-8
// (value desc, index asc on ties).  Indices written as float values.
// ============================================================================
__global__ __launch_bounds__(256) void softmax_topk_kernel(
    float* __restrict__ att, float* __restrict__ out_idx) {
  const int row  = blockIdx.x * 4 + (threadIdx.x >> 6);  // t*B + b
  const int lane = threadIdx.x & 63;

  float* s = att + (size_t)row * N_;
  const float4 v4 = *(const float4*)(s + 4 * lane);
  const float v[4] = {v4.x, v4.y, v4.z, v4.w};

  float m = fmaxf(fmaxf(v[0], v[1]), fmaxf(v[2], v[3]));
#pragma unroll
  for (int d = 1; d < 64; d <<= 1) m = fmaxf(m, __shfl_xor(m, d));

  float p[4];
#pragma unroll
  for (int e = 0; e < 4; ++e) p[e] = expf(SCALE * (v[e] - m));

  float sum = p[0] + p[1] + p[2] + p[3];
#pragma unroll
  for (int d = 1; d < 64; d <<= 1) sum += __shfl_xor(sum, d);
  const float inv = 1.0f / sum;

  float a[4];
#pragma unroll
  for (int e = 0; e < 4; ++e) a[e] = p[e] * inv;

  *(float4*)(s + 4 * lane) = make_float4(a[0], a[1], a[2], a[3]);

  float w[4] = {a[0], a[1], a[2], a[3]};
  for (int kk = 0; kk < K_; ++kk) {
    float bv = w[0];
    int bn = 4 * lane;
#pragma unroll
    for (int e = 1; e < 4; ++e) {
      if (w[e] > bv) { bv = w[e]; bn = 4 * lane + e; }
    }
#pragma unroll
    for (int d = 1; d < 64; d <<= 1) {
      const float ov = __shfl_xor(bv, d);
      const int on = __shfl_xor(bn, d);
      if (ov > bv || (ov == bv && on < bn)) { bv = ov; bn = on; }
    }
    if (lane == 0) out_idx[kk * (T_ * B_) + row] = (float)bn;  // (k,T,B)
#pragma unroll
    for (int e = 0; e < 4; ++e)
      if (4 * lane + e == bn) w[e] = -1.0f;
  }
}

extern "C" void kernel_launch(void* const* d_in, const int* in_sizes, int n_in,
                              void* d_out, int out_size, void* d_ws,
                              size_t ws_size, hipStream_t stream) {
  const float* q    = (const float*)d_in[0];   // (T,1,B,H) fp32
  const float* keys = (const float*)d_in[1];   // (N,B,L*H) fp32
  float* out = (float*)d_out;
  float* att = out;                 // 65536 floats: raw scores -> attention
  float* idx = out + T_ * B_ * N_;  // 2048 floats: (k,T,B) indices as floats

  score_kernel<<<B_ * (N_ / 4), 256, 0, stream>>>(q, keys, att);
  softmax_topk_kernel<<<(T_ * B_) / 4, 256, 0, stream>>>(att, idx);
}